// Round 10
// baseline (2753.458 us; speedup 1.0000x reference)
//
#include <hip/hip_runtime.h>
#include <hip/hip_bf16.h>
#include <cstdint>
#include <cstddef>

#define B_TOT   16384
#define F_DIM   1024
#define P_TOT   1024
#define K_IN    9
#define W_H     10
#define TB      64      // batch rows per block
#define THREADS 1024    // 16 waves
#define NWAVE   16
#define LSTR    1028    // LDS x row stride in BYTES (fp8); conflict-free gathers
#define XS_BYTES (TB * LSTR)            // 65792
// weight record: [0..8]=idx, [9]=pad, [10..99]=W1, [100..109]=b1,
// [110..209]=W2, [210..219]=b2, [220..229]=W3, [230]=b3, [231]=wl
#define REC_DW   232
#define IT_P     NWAVE                  // 16 patches per iteration (1 per wave)
#define NITER    (P_TOT / IT_P)         // 64
#define STG_DW   (IT_P * REC_DW)        // 3712 dwords per iteration
#define STG_V4   (STG_DW / 4)           // 928 uint4 per iteration
#define WBUF_B   (STG_DW * 4)           // 14848 B per buffer
#define WS_BYTES (P_TOT * REC_DW * 4)   // 950272 B

typedef float f32x2 __attribute__((ext_vector_type(2)));

__device__ __forceinline__ float fast_exp2(float x) {
#if __has_builtin(__builtin_amdgcn_exp2f)
    return __builtin_amdgcn_exp2f(x);
#else
    return exp2f(x);
#endif
}
__device__ __forceinline__ float fast_rcp(float x) {
#if __has_builtin(__builtin_amdgcn_rcpf)
    return __builtin_amdgcn_rcpf(x);
#else
    return 1.0f / x;
#endif
}
// tanh(x) = 1 - 2/(exp(2x)+1); robust at +-inf
__device__ __forceinline__ float tanh_fast(float x) {
    float t = fast_exp2(x * 2.8853900817779268f);
    return fmaf(-2.0f, fast_rcp(t + 1.0f), 1.0f);
}
__device__ __forceinline__ f32x2 ld2(const float* p) {
    return *reinterpret_cast<const f32x2*>(p);   // even-dword offsets -> 8B aligned
}
__device__ __forceinline__ f32x2 pkfma(f32x2 a, f32x2 b, f32x2 c) {
#if __has_builtin(__builtin_elementwise_fma)
    return __builtin_elementwise_fma(a, b, c);   // -> v_pk_fma_f32
#else
    return f32x2{fmaf(a[0], b[0], c[0]), fmaf(a[1], b[1], c[1])};
#endif
}

// ---- prep: pack per-patch weight records into ws ----
__global__ void prep_records(const int* __restrict__ idx,
                             const float* __restrict__ W1, const float* __restrict__ b1,
                             const float* __restrict__ W2, const float* __restrict__ b2,
                             const float* __restrict__ W3, const float* __restrict__ b3,
                             const float* __restrict__ wl, uint32_t* __restrict__ ws)
{
    const int p = blockIdx.x;
    const int t = threadIdx.x;            // 0..231
    uint32_t v = 0;
    if (t < 9)        v = (uint32_t)idx[p * 9 + t];
    else if (t == 9)  v = 0;
    else if (t < 100) v = __float_as_uint(W1[p * 90  + (t - 10)]);
    else if (t < 110) v = __float_as_uint(b1[p * 10  + (t - 100)]);
    else if (t < 210) v = __float_as_uint(W2[p * 100 + (t - 110)]);
    else if (t < 220) v = __float_as_uint(b2[p * 10  + (t - 210)]);
    else if (t < 230) v = __float_as_uint(W3[p * 10  + (t - 220)]);
    else if (t == 230) v = __float_as_uint(b3[p]);
    else               v = __float_as_uint(wl[p]);
    ws[p * REC_DW + t] = v;
}

__global__ __launch_bounds__(THREADS, 4)
void dnn_main(const float* __restrict__ x, const uint32_t* __restrict__ ws,
              const float* __restrict__ wl, float* __restrict__ out)
{
    extern __shared__ unsigned char xs[];   // [XS_BYTES] x tile + 2 weight buffers
    __shared__ float partial[NWAVE][TB];

    const int tid = threadIdx.x;
    const int b0  = blockIdx.x * TB;

    // ---- stage x tile (fp32 global, coalesced float4) -> fp8 LDS ----
    #pragma unroll
    for (int i = 0; i < (TB * (F_DIM / 4)) / THREADS; ++i) {   // 16 iters
        const int q   = i * THREADS + tid;
        const int row = q >> 8;
        const int c4  = q & 255;
        const float4 v = *reinterpret_cast<const float4*>(
            x + (size_t)(b0 + row) * F_DIM + (c4 << 2));
        int pk = __builtin_amdgcn_cvt_pk_fp8_f32(v.x, v.y, 0, false);
        pk     = __builtin_amdgcn_cvt_pk_fp8_f32(v.z, v.w, pk, true);
        *reinterpret_cast<uint32_t*>(xs + row * LSTR + (c4 << 2)) = (uint32_t)pk;
    }

    // ---- stage weight records for iteration 0 ----
    const uint4* __restrict__ ws4 = reinterpret_cast<const uint4*>(ws);
    const bool loader = (tid < STG_V4);
    if (loader)
        reinterpret_cast<uint4*>(xs + XS_BYTES)[tid] = ws4[tid];
    __syncthreads();

    const int lane = tid & 63;           // lane = local batch row
    const int wave = tid >> 6;
    const unsigned char* __restrict__ myrow = xs + lane * LSTR;

    float yacc = 0.0f;
    int cur = 0;

    for (int it = 0; it < NITER; ++it) {   // 64 iters, 1 patch per wave each
        // issue next iteration's record loads early (latency hides under compute)
        uint4 stg;
        const bool pre = loader && (it + 1 < NITER);
        if (pre) stg = ws4[(it + 1) * STG_V4 + tid];

        // ---- compute from LDS record ----
        const uint32_t* rec32 = reinterpret_cast<const uint32_t*>(
            xs + XS_BYTES + cur * WBUF_B + wave * (REC_DW * 4));
        const int*   __restrict__ ip  = reinterpret_cast<const int*>(rec32);
        const float* __restrict__ rf  = reinterpret_cast<const float*>(rec32);
        const float* __restrict__ W1p = rf + 10;
        const float* __restrict__ b1p = rf + 100;
        const float* __restrict__ W2p = rf + 110;
        const float* __restrict__ b2p = rf + 210;
        const float* __restrict__ W3p = rf + 220;

        // gather 9 features from LDS (conflict-free: stride 1028 B)
        float xg[K_IN];
        #pragma unroll
        for (int k = 0; k < K_IN; ++k)
            xg[k] = __builtin_amdgcn_cvt_f32_fp8((int)myrow[ip[k]], 0);

        // layer 1: (9 -> 10) + tanh, packed fp32 over output pairs
        f32x2 H[5];
        #pragma unroll
        for (int j = 0; j < 5; ++j) H[j] = ld2(b1p + 2 * j);
        #pragma unroll
        for (int k = 0; k < K_IN; ++k) {
            const f32x2 xk2 = {xg[k], xg[k]};
            #pragma unroll
            for (int j = 0; j < 5; ++j)
                H[j] = pkfma(xk2, ld2(W1p + k * W_H + 2 * j), H[j]);
        }
        float h1[W_H];
        #pragma unroll
        for (int j = 0; j < 5; ++j) {
            h1[2 * j]     = tanh_fast(H[j][0]);
            h1[2 * j + 1] = tanh_fast(H[j][1]);
        }

        // layer 2: (10 -> 10), packed fp32 over output pairs
        f32x2 G[5];
        #pragma unroll
        for (int j = 0; j < 5; ++j) G[j] = ld2(b2p + 2 * j);
        #pragma unroll
        for (int w = 0; w < W_H; ++w) {
            const f32x2 hw2 = {h1[w], h1[w]};
            #pragma unroll
            for (int j = 0; j < 5; ++j)
                G[j] = pkfma(hw2, ld2(W2p + w * W_H + 2 * j), G[j]);
        }

        // layer 3: (10 -> 1), packed pairwise then horizontal add
        f32x2 acc2 = {rf[230], 0.0f};
        #pragma unroll
        for (int j = 0; j < 5; ++j)
            acc2 = pkfma(G[j], ld2(W3p + 2 * j), acc2);
        const float lo = acc2[0] + acc2[1];

        yacc = fmaf(lo, rf[231], yacc);

        // ---- write prefetched records into the other buffer, flip ----
        if (pre)
            reinterpret_cast<uint4*>(xs + XS_BYTES + (cur ^ 1) * WBUF_B)[tid] = stg;
        __syncthreads();
        cur ^= 1;
    }

    partial[wave][lane] = yacc;
    __syncthreads();

    // ---- block reduction over the 16 waves + outputs (single writer) ----
    if (tid < TB) {
        float s = 0.0f;
        #pragma unroll
        for (int w = 0; w < NWAVE; ++w) s += partial[w][tid];
        out[b0 + tid] = s;

        // channel 2: sum(|w_last|), computed redundantly per row-block
        float sa = 0.0f;
        #pragma unroll
        for (int i = 0; i < P_TOT / TB; ++i) sa += fabsf(wl[tid + TB * i]);
        #pragma unroll
        for (int off = 32; off > 0; off >>= 1) sa += __shfl_down(sa, off);
        sa = __shfl(sa, 0);
        out[B_TOT + b0 + tid] = sa;
    }
}

// ================= fallback (R8 kernel, scalar-path weights) =================
#define PGRP    2
#define PPB     (P_TOT / PGRP)

__global__ __launch_bounds__(THREADS, 8)
void dnn_fallback(const float* __restrict__ x, const int* __restrict__ idx,
                  const float* __restrict__ W1, const float* __restrict__ b1,
                  const float* __restrict__ W2, const float* __restrict__ b2,
                  const float* __restrict__ W3, const float* __restrict__ b3,
                  const float* __restrict__ wl, float* __restrict__ out)
{
    extern __shared__ unsigned char xs[];
    __shared__ float partial[NWAVE][TB];
    const int tid = threadIdx.x;
    const int b0  = blockIdx.x * TB;
    const int p0  = blockIdx.y * PPB;
    #pragma unroll
    for (int i = 0; i < (TB * (F_DIM / 4)) / THREADS; ++i) {
        const int q = i * THREADS + tid;
        const int row = q >> 8, c4 = q & 255;
        const float4 v = *reinterpret_cast<const float4*>(
            x + (size_t)(b0 + row) * F_DIM + (c4 << 2));
        int pk = __builtin_amdgcn_cvt_pk_fp8_f32(v.x, v.y, 0, false);
        pk     = __builtin_amdgcn_cvt_pk_fp8_f32(v.z, v.w, pk, true);
        *reinterpret_cast<uint32_t*>(xs + row * LSTR + (c4 << 2)) = (uint32_t)pk;
    }
    __syncthreads();
    const int lane = tid & 63, wave = tid >> 6;
    const unsigned char* __restrict__ myrow = xs + lane * LSTR;
    float yacc = 0.0f;
    for (int jp = 0; jp < PPB / NWAVE; ++jp) {
        const int p = __builtin_amdgcn_readfirstlane(p0 + jp * NWAVE + wave);
        const int* __restrict__ ip = idx + p * K_IN;
        const float* __restrict__ W1p = W1 + p * (K_IN * W_H);
        const float* __restrict__ b1p = b1 + p * W_H;
        const float* __restrict__ W2p = W2 + p * (W_H * W_H);
        const float* __restrict__ b2p = b2 + p * W_H;
        const float* __restrict__ W3p = W3 + p * W_H;
        float xg[K_IN];
        #pragma unroll
        for (int k = 0; k < K_IN; ++k)
            xg[k] = __builtin_amdgcn_cvt_f32_fp8((int)myrow[ip[k]], 0);
        f32x2 H[5];
        #pragma unroll
        for (int j = 0; j < 5; ++j) H[j] = ld2(b1p + 2 * j);
        #pragma unroll
        for (int k = 0; k < K_IN; ++k) {
            const f32x2 xk2 = {xg[k], xg[k]};
            #pragma unroll
            for (int j = 0; j < 5; ++j)
                H[j] = pkfma(xk2, ld2(W1p + k * W_H + 2 * j), H[j]);
        }
        float h1[W_H];
        #pragma unroll
        for (int j = 0; j < 5; ++j) {
            h1[2 * j]     = tanh_fast(H[j][0]);
            h1[2 * j + 1] = tanh_fast(H[j][1]);
        }
        f32x2 G[5];
        #pragma unroll
        for (int j = 0; j < 5; ++j) G[j] = ld2(b2p + 2 * j);
        #pragma unroll
        for (int w = 0; w < W_H; ++w) {
            const f32x2 hw2 = {h1[w], h1[w]};
            #pragma unroll
            for (int j = 0; j < 5; ++j)
                G[j] = pkfma(hw2, ld2(W2p + w * W_H + 2 * j), G[j]);
        }
        f32x2 acc2 = {b3[p], 0.0f};
        #pragma unroll
        for (int j = 0; j < 5; ++j)
            acc2 = pkfma(G[j], ld2(W3p + 2 * j), acc2);
        yacc = fmaf(acc2[0] + acc2[1], wl[p], yacc);
    }
    partial[wave][lane] = yacc;
    __syncthreads();
    if (tid < TB) {
        float s = 0.0f;
        #pragma unroll
        for (int w = 0; w < NWAVE; ++w) s += partial[w][tid];
        atomicAdd(&out[b0 + tid], s);
        if (blockIdx.y == 0) {
            float sa = 0.0f;
            #pragma unroll
            for (int i = 0; i < P_TOT / TB; ++i) sa += fabsf(wl[tid + TB * i]);
            #pragma unroll
            for (int off = 32; off > 0; off >>= 1) sa += __shfl_down(sa, off);
            sa = __shfl(sa, 0);
            out[B_TOT + b0 + tid] = sa;
        }
    }
}

extern "C" void kernel_launch(void* const* d_in, const int* in_sizes, int n_in,
                              void* d_out, int out_size, void* d_ws, size_t ws_size,
                              hipStream_t stream)
{
    const float* x  = (const float*)d_in[0];
    const int*   idx= (const int*)  d_in[1];
    const float* W1 = (const float*)d_in[2];
    const float* b1 = (const float*)d_in[3];
    const float* W2 = (const float*)d_in[4];
    const float* b2 = (const float*)d_in[5];
    const float* W3 = (const float*)d_in[6];
    const float* b3 = (const float*)d_in[7];
    const float* wl = (const float*)d_in[8];
    float* out = (float*)d_out;

    if (ws_size >= (size_t)WS_BYTES) {
        uint32_t* ws = (uint32_t*)d_ws;
        prep_records<<<P_TOT, REC_DW, 0, stream>>>(idx, W1, b1, W2, b2, W3, b3, wl, ws);

        const int smem = XS_BYTES + 2 * WBUF_B;   // 95488 B dynamic LDS
        (void)hipFuncSetAttribute(reinterpret_cast<const void*>(dnn_main),
                                  hipFuncAttributeMaxDynamicSharedMemorySize, smem);
        dnn_main<<<B_TOT / TB, THREADS, smem, stream>>>(x, ws, wl, out);
    } else {
        (void)hipMemsetAsync(out, 0, B_TOT * sizeof(float), stream);
        const int smem = XS_BYTES;
        (void)hipFuncSetAttribute(reinterpret_cast<const void*>(dnn_fallback),
                                  hipFuncAttributeMaxDynamicSharedMemorySize, smem);
        dim3 grid(B_TOT / TB, PGRP);
        dnn_fallback<<<grid, THREADS, smem, stream>>>(x, idx, W1, b1, W2, b2, W3, b3, wl, out);
    }
}

// Round 11
// 150.038 us; speedup vs baseline: 18.3517x; 18.3517x over previous
//
#include <hip/hip_runtime.h>
#include <hip/hip_bf16.h>
#include <cstdint>
#include <cstddef>

#define B_TOT   16384
#define F_DIM   1024
#define P_TOT   1024
#define K_IN    9
#define W_H     10
#define TB      128     // batch rows per block (2 per lane)
#define THREADS 1024    // 16 waves
#define NWAVE   16
#define PGRP    2       // patch groups (P split across blocks)
#define PPB     (P_TOT / PGRP)   // 512 patches per block
#define LSTR    1028    // LDS x row stride in BYTES (fp8); conflict-free gathers

typedef float f32x2 __attribute__((ext_vector_type(2)));

__device__ __forceinline__ float fast_exp2(float x) {
#if __has_builtin(__builtin_amdgcn_exp2f)
    return __builtin_amdgcn_exp2f(x);
#else
    return exp2f(x);
#endif
}
__device__ __forceinline__ float fast_rcp(float x) {
#if __has_builtin(__builtin_amdgcn_rcpf)
    return __builtin_amdgcn_rcpf(x);
#else
    return 1.0f / x;
#endif
}
// tanh(x) = 1 - 2/(exp(2x)+1); robust at +-inf
__device__ __forceinline__ float tanh_fast(float x) {
    float t = fast_exp2(x * 2.8853900817779268f);
    return fmaf(-2.0f, fast_rcp(t + 1.0f), 1.0f);
}
__device__ __forceinline__ f32x2 ld2(const float* p) {
    return *reinterpret_cast<const f32x2*>(p);   // even-dword offsets -> 8B aligned
}
__device__ __forceinline__ f32x2 pkfma(f32x2 a, f32x2 b, f32x2 c) {
#if __has_builtin(__builtin_elementwise_fma)
    return __builtin_elementwise_fma(a, b, c);   // -> v_pk_fma_f32
#else
    return f32x2{fmaf(a[0], b[0], c[0]), fmaf(a[1], b[1], c[1])};
#endif
}

__global__ __launch_bounds__(THREADS, 4)
void dnn_fused(const float* __restrict__ x, const int* __restrict__ idx,
               const float* __restrict__ W1, const float* __restrict__ b1,
               const float* __restrict__ W2, const float* __restrict__ b2,
               const float* __restrict__ W3, const float* __restrict__ b3,
               const float* __restrict__ wl, float* __restrict__ out)
{
    extern __shared__ unsigned char xs[];        // [TB][LSTR] fp8(e4m3) x tile, 131584 B
    __shared__ float partial[NWAVE][TB];         // 8 KB static

    const int tid = threadIdx.x;
    const int b0  = blockIdx.x * TB;
    const int p0  = blockIdx.y * PPB;

    // ---- stage x tile (fp32 global, coalesced float4) -> fp8 LDS ----
    #pragma unroll
    for (int i = 0; i < (TB * (F_DIM / 4)) / THREADS; ++i) {   // 32 iters
        const int q   = i * THREADS + tid;
        const int row = q >> 8;          // 256 float4 per row
        const int c4  = q & 255;
        const float4 v = *reinterpret_cast<const float4*>(
            x + (size_t)(b0 + row) * F_DIM + (c4 << 2));
        int pk = __builtin_amdgcn_cvt_pk_fp8_f32(v.x, v.y, 0, false);
        pk     = __builtin_amdgcn_cvt_pk_fp8_f32(v.z, v.w, pk, true);
        *reinterpret_cast<uint32_t*>(xs + row * LSTR + (c4 << 2)) = (uint32_t)pk;
    }
    __syncthreads();

    const int lane = tid & 63;
    const int wave = tid >> 6;
    const unsigned char* __restrict__ row0 = xs + lane * LSTR;          // batch row b0+lane
    const unsigned char* __restrict__ row1 = xs + (lane + 64) * LSTR;   // batch row b0+lane+64

    float y0 = 0.0f, y1 = 0.0f;

    // 1 patch per wave per iteration, 2 batch rows per lane: ONE scalar
    // weight-fetch chain is amortized over 2x the compute (vs R8)
    for (int jp = 0; jp < PPB / NWAVE; ++jp) {   // 32 iters
        const int p = __builtin_amdgcn_readfirstlane(p0 + jp * NWAVE + wave);
        const int*   __restrict__ ip  = idx + p * K_IN;
        const float* __restrict__ W1p = W1 + p * (K_IN * W_H);
        const float* __restrict__ b1p = b1 + p * W_H;
        const float* __restrict__ W2p = W2 + p * (W_H * W_H);
        const float* __restrict__ b2p = b2 + p * W_H;
        const float* __restrict__ W3p = W3 + p * W_H;

        // gather 9 features for both rows (conflict-free: stride 1028 B)
        float xg0[K_IN], xg1[K_IN];
        #pragma unroll
        for (int k = 0; k < K_IN; ++k) {
            const int c = ip[k];
            xg0[k] = __builtin_amdgcn_cvt_f32_fp8((int)row0[c], 0);
            xg1[k] = __builtin_amdgcn_cvt_f32_fp8((int)row1[c], 0);
        }

        // layer 1: (9 -> 10) + tanh, packed fp32 over output pairs, 2 rows
        f32x2 H0[5], H1[5];
        #pragma unroll
        for (int j = 0; j < 5; ++j) { const f32x2 b = ld2(b1p + 2 * j); H0[j] = b; H1[j] = b; }
        #pragma unroll
        for (int k = 0; k < K_IN; ++k) {
            const f32x2 xa = {xg0[k], xg0[k]};
            const f32x2 xb = {xg1[k], xg1[k]};
            #pragma unroll
            for (int j = 0; j < 5; ++j) {
                const f32x2 w = ld2(W1p + k * W_H + 2 * j);   // shared by both rows
                H0[j] = pkfma(xa, w, H0[j]);
                H1[j] = pkfma(xb, w, H1[j]);
            }
        }
        float h10[W_H], h11[W_H];
        #pragma unroll
        for (int j = 0; j < 5; ++j) {
            h10[2 * j]     = tanh_fast(H0[j][0]);
            h10[2 * j + 1] = tanh_fast(H0[j][1]);
            h11[2 * j]     = tanh_fast(H1[j][0]);
            h11[2 * j + 1] = tanh_fast(H1[j][1]);
        }

        // layer 2: (10 -> 10), packed fp32 over output pairs, 2 rows
        f32x2 G0[5], G1[5];
        #pragma unroll
        for (int j = 0; j < 5; ++j) { const f32x2 b = ld2(b2p + 2 * j); G0[j] = b; G1[j] = b; }
        #pragma unroll
        for (int w = 0; w < W_H; ++w) {
            const f32x2 ha = {h10[w], h10[w]};
            const f32x2 hb = {h11[w], h11[w]};
            #pragma unroll
            for (int j = 0; j < 5; ++j) {
                const f32x2 wv = ld2(W2p + w * W_H + 2 * j);  // shared by both rows
                G0[j] = pkfma(ha, wv, G0[j]);
                G1[j] = pkfma(hb, wv, G1[j]);
            }
        }

        // layer 3: (10 -> 1), packed pairwise then horizontal add, 2 rows
        const float b3p = b3[p];
        f32x2 a0 = {b3p, 0.0f}, a1 = {b3p, 0.0f};
        #pragma unroll
        for (int j = 0; j < 5; ++j) {
            const f32x2 wv = ld2(W3p + 2 * j);                // shared by both rows
            a0 = pkfma(G0[j], wv, a0);
            a1 = pkfma(G1[j], wv, a1);
        }
        const float wlp = wl[p];
        y0 = fmaf(a0[0] + a0[1], wlp, y0);
        y1 = fmaf(a1[0] + a1[1], wlp, y1);
    }

    partial[wave][lane]      = y0;
    partial[wave][lane + 64] = y1;
    __syncthreads();

    // ---- block reduction over the 16 waves + outputs ----
    if (tid < TB) {
        float s = 0.0f;
        #pragma unroll
        for (int w = 0; w < NWAVE; ++w) s += partial[w][tid];
        // two blocks (pgroups) contribute per y element; fp32 add is
        // commutative -> bitwise deterministic regardless of arrival order
        atomicAdd(&out[b0 + tid], s);
    }

    if (blockIdx.y == 0 && tid < 64) {
        // channel 2: sum(|w_last|), computed redundantly per row-block
        float sa = 0.0f;
        #pragma unroll
        for (int i = 0; i < P_TOT / 64; ++i) sa += fabsf(wl[tid + 64 * i]);
        #pragma unroll
        for (int off = 32; off > 0; off >>= 1) sa += __shfl_down(sa, off);
        sa = __shfl(sa, 0);
        out[B_TOT + b0 + tid]      = sa;   // single writer per element
        out[B_TOT + b0 + 64 + tid] = sa;
    }
}

extern "C" void kernel_launch(void* const* d_in, const int* in_sizes, int n_in,
                              void* d_out, int out_size, void* d_ws, size_t ws_size,
                              hipStream_t stream)
{
    const float* x  = (const float*)d_in[0];
    const int*   idx= (const int*)  d_in[1];
    const float* W1 = (const float*)d_in[2];
    const float* b1 = (const float*)d_in[3];
    const float* W2 = (const float*)d_in[4];
    const float* b2 = (const float*)d_in[5];
    const float* W3 = (const float*)d_in[6];
    const float* b3 = (const float*)d_in[7];
    const float* wl = (const float*)d_in[8];
    float* out = (float*)d_out;

    // zero the y channel (atomicAdd accumulates into it)
    (void)hipMemsetAsync(out, 0, B_TOT * sizeof(float), stream);

    const int smem = TB * LSTR;  // 131584 B dynamic LDS (>64KB -> opt in)
    (void)hipFuncSetAttribute(reinterpret_cast<const void*>(dnn_fused),
                              hipFuncAttributeMaxDynamicSharedMemorySize, smem);

    dim3 grid(B_TOT / TB, PGRP);   // 128 x 2 = 256 blocks
    dnn_fused<<<grid, THREADS, smem, stream>>>(x, idx, W1, b1, W2, b2, W3, b3, wl, out);
}